// Round 6
// baseline (65.472 us; speedup 1.0000x reference)
//
#include <hip/hip_runtime.h>

// PGA G(3,0,1) geometric product, pairwise: out[n,m,:] = T[n] * reverse(T[m]).
// R3b: single fused kernel. Per-block b-tile staged coalesced->LDS (padded
// stride 20), LDS region reused for the output store-transpose (one barrier
// total), nontemporal dwordx4 stores via clang ext-vector float4 (HIP float4
// is a struct and rejected by __builtin_nontemporal_store).

namespace {

typedef float f2 __attribute__((ext_vector_type(2)));
typedef float f4 __attribute__((ext_vector_type(4)));

constexpr int popcount4(unsigned x) {
    int c = 0;
    for (int i = 0; i < 5; ++i) c += (x >> i) & 1;
    return c;
}

struct GPTab {
    signed char sgn[16][16];
    unsigned char idx[16][16];
};

// Blade bitmasks in the reference's basis order:
// (), e0..e3, e01,e02,e03,e12,e13,e23, e012,e013,e023,e123, e0123
constexpr unsigned MASKV[16] = {0u, 1u, 2u, 4u, 8u,
                                3u, 5u, 9u, 6u, 10u, 12u,
                                7u, 11u, 13u, 14u, 15u};

constexpr GPTab make_tab() {
    GPTab t{};
    int inv[16] = {};
    for (int i = 0; i < 16; ++i) inv[(int)MASKV[i]] = i;

    for (int j = 0; j < 16; ++j) {
        for (int k = 0; k < 16; ++k) {
            unsigned a = MASKV[j], b = MASKV[k];
            if (a & b & 1u) {            // shared e0 -> e0^2 = 0
                t.sgn[j][k] = 0;
                t.idx[j][k] = 0;
                continue;
            }
            int swaps = 0;
            for (int g = 0; g < 4; ++g)
                if ((b >> g) & 1u)
                    swaps += popcount4(a >> (g + 1));
            int s = (swaps & 1) ? -1 : 1;
            int r = popcount4(b);
            if ((r * (r - 1) / 2) & 1) s = -s;   // reverse() on 2nd operand
            t.sgn[j][k] = (signed char)s;
            t.idx[j][k] = (unsigned char)inv[(int)(a ^ b)];
        }
    }
    return t;
}

// Packing of the 16 blades into 8 float2 slots, paired by the e1 bit.
struct Packing {
    unsigned char pl[8], ph[8];
    unsigned char slot[16], half[16];
    signed char   act[16][8];
    unsigned char src[16][8];
    unsigned char swp[16][8];
    signed char   s0[16][8], s1[16][8];
};

constexpr Packing make_packing() {
    Packing p{};
    int inv[16] = {};
    for (int i = 0; i < 16; ++i) inv[(int)MASKV[i]] = i;

    int t = 0;
    for (int e0bit = 0; e0bit <= 1; ++e0bit) {
        for (unsigned m = 0; m < 16; ++m) {
            if ((m & 2u) == 0u && (int)(m & 1u) == e0bit) {
                int lo = inv[(int)m], hi = inv[(int)(m | 2u)];
                p.pl[t] = (unsigned char)lo;
                p.ph[t] = (unsigned char)hi;
                p.slot[lo] = (unsigned char)t; p.half[lo] = 0;
                p.slot[hi] = (unsigned char)t; p.half[hi] = 1;
                ++t;
            }
        }
    }

    GPTab tab = make_tab();
    for (int k = 0; k < 16; ++k) {
        for (int s = 0; s < 8; ++s) {
            int i0 = p.pl[s], i1 = p.ph[s];
            int j0 = inv[(int)(MASKV[i0] ^ MASKV[k])];
            int j1 = inv[(int)(MASKV[i1] ^ MASKV[k])];
            int g0 = tab.sgn[j0][k], g1 = tab.sgn[j1][k];
            p.act[k][s] = (signed char)(g0 != 0);
            p.src[k][s] = p.slot[j0];
            p.swp[k][s] = p.half[j0];
            p.s0[k][s] = (signed char)g0;
            p.s1[k][s] = (signed char)g1;
        }
    }
    return p;
}

constexpr Packing PK = make_packing();

} // namespace

// Requires nrows % 256 == 0 (harness: nrows = 2048).
__global__ __launch_bounds__(256) void gp_fused_kernel(
    const float* __restrict__ T, float* __restrict__ out, int nrows) {
    const int lane = threadIdx.x & 63;
    const int wave = threadIdx.x >> 6;
    const int t    = threadIdx.x;
    const int m0   = blockIdx.x * 256;
    const int n    = blockIdx.y;              // wave-uniform

    // 256 pairs x 20-float padded stride (80 B, 16B-aligned). 20 KB.
    // Used twice: (1) b-operand tile, (2) per-wave output store-transpose.
    __shared__ float lds[256 * 20];

    // ---- stage b-tile: 16 KB contiguous from T, fully coalesced ----
    {
        const f4* __restrict__ src =
            reinterpret_cast<const f4*>(T) + (size_t)m0 * 4;
#pragma unroll
        for (int k2 = 0; k2 < 4; ++k2) {
            const int g = k2 * 256 + t;       // float4 id within the tile
            f4 v = src[g];
            const int p = g >> 2, c = g & 3;
            *reinterpret_cast<f4*>(&lds[p * 20 + c * 4]) = v;
        }
    }
    __syncthreads();                          // the only barrier

    // ---- operands ----
    float a[16], b[16];
#pragma unroll
    for (int q = 0; q < 4; ++q) {             // uniform -> scalar/broadcast
        f4 va = reinterpret_cast<const f4*>(T)[(size_t)n * 4 + q];
        a[q * 4 + 0] = va.x; a[q * 4 + 1] = va.y;
        a[q * 4 + 2] = va.z; a[q * 4 + 3] = va.w;
    }
#pragma unroll
    for (int q = 0; q < 4; ++q) {             // stride-20 -> bank-minimal
        f4 vb = *reinterpret_cast<const f4*>(&lds[t * 20 + q * 4]);
        b[q * 4 + 0] = vb.x; b[q * 4 + 1] = vb.y;
        b[q * 4 + 2] = vb.z; b[q * 4 + 3] = vb.w;
    }

    // ---- packed geometric product (96 v_pk_fma_f32) ----
    f2 A[8];
#pragma unroll
    for (int s = 0; s < 8; ++s) {
        f2 v; v.x = a[PK.pl[s]]; v.y = a[PK.ph[s]];
        A[s] = v;
    }

    f2 O[8];
#pragma unroll
    for (int s = 0; s < 8; ++s) O[s] = (f2)(0.0f);

#pragma unroll
    for (int k = 0; k < 16; ++k) {
        const float bk = b[k];
        f2 bb; bb.x = bk; bb.y = bk;
#pragma unroll
        for (int s = 0; s < 8; ++s) {
            if (PK.act[k][s]) {               // compile-time after unroll
                const f2 srcv = A[PK.src[k][s]];
                float x = PK.swp[k][s] ? srcv.y : srcv.x;
                float y = PK.swp[k][s] ? srcv.x : srcv.y;
                if (PK.s0[k][s] < 0) x = -x;
                if (PK.s1[k][s] < 0) y = -y;
                f2 av; av.x = x; av.y = y;
                O[s] = __builtin_elementwise_fma(av, bb, O[s]);
            }
        }
    }

    float o[16];
#pragma unroll
    for (int i = 0; i < 16; ++i)
        o[i] = PK.half[i] ? O[PK.slot[i]].y : O[PK.slot[i]].x;

    // ---- output store-transpose, reusing the SAME LDS region ----
    // Thread t overwrites exactly the region it (alone) read b from, and the
    // readback stays within this wave's region; same-wave DS ordering makes
    // this barrier-free.
    float* w = &lds[t * 20];
#pragma unroll
    for (int q = 0; q < 4; ++q) {
        f4 v; v.x = o[q * 4 + 0]; v.y = o[q * 4 + 1];
        v.z = o[q * 4 + 2]; v.w = o[q * 4 + 3];
        *reinterpret_cast<f4*>(w + q * 4) = v;
    }

    const int waveM0 = m0 + wave * 64;
    f4* __restrict__ ov =
        reinterpret_cast<f4*>(out) + ((size_t)n * nrows + waveM0) * 4;
    const float* wbase = &lds[wave * 64 * 20];
#pragma unroll
    for (int q = 0; q < 4; ++q) {
        const int g = q * 64 + lane;          // float4 index within wave tile
        const int p = g >> 2;
        const int c = g & 3;
        f4 v = *reinterpret_cast<const f4*>(&wbase[p * 20 + c * 4]);
        __builtin_nontemporal_store(v, ov + g);
    }
}

extern "C" void kernel_launch(void* const* d_in, const int* in_sizes, int n_in,
                              void* d_out, int out_size, void* d_ws, size_t ws_size,
                              hipStream_t stream) {
    const float* T = (const float*)d_in[0];
    float* out = (float*)d_out;
    const int nrows = in_sizes[0] / 16;       // 2048 (multiple of 256)
    dim3 grid((unsigned)(nrows / 256), (unsigned)nrows, 1);
    gp_fused_kernel<<<grid, 256, 0, stream>>>(T, out, nrows);
}

// Round 7
// 53.687 us; speedup vs baseline: 1.2195x; 1.2195x over previous
//
#include <hip/hip_runtime.h>

// PGA G(3,0,1) geometric product, pairwise: out[n,m,:] = T[n] * reverse(T[m]).
// R4: R3b structure (single fused kernel, b-tile staged in LDS, LDS region
// reused for output store-transpose, one barrier) but with PLAIN dwordx4
// stores — R3b showed nontemporal stores cost ~16 us (bypass L2
// write-combining; fill kernel's 7 TB/s goes through L2).

namespace {

typedef float f2 __attribute__((ext_vector_type(2)));
typedef float f4 __attribute__((ext_vector_type(4)));

constexpr int popcount4(unsigned x) {
    int c = 0;
    for (int i = 0; i < 5; ++i) c += (x >> i) & 1;
    return c;
}

struct GPTab {
    signed char sgn[16][16];
    unsigned char idx[16][16];
};

// Blade bitmasks in the reference's basis order:
// (), e0..e3, e01,e02,e03,e12,e13,e23, e012,e013,e023,e123, e0123
constexpr unsigned MASKV[16] = {0u, 1u, 2u, 4u, 8u,
                                3u, 5u, 9u, 6u, 10u, 12u,
                                7u, 11u, 13u, 14u, 15u};

constexpr GPTab make_tab() {
    GPTab t{};
    int inv[16] = {};
    for (int i = 0; i < 16; ++i) inv[(int)MASKV[i]] = i;

    for (int j = 0; j < 16; ++j) {
        for (int k = 0; k < 16; ++k) {
            unsigned a = MASKV[j], b = MASKV[k];
            if (a & b & 1u) {            // shared e0 -> e0^2 = 0
                t.sgn[j][k] = 0;
                t.idx[j][k] = 0;
                continue;
            }
            int swaps = 0;
            for (int g = 0; g < 4; ++g)
                if ((b >> g) & 1u)
                    swaps += popcount4(a >> (g + 1));
            int s = (swaps & 1) ? -1 : 1;
            int r = popcount4(b);
            if ((r * (r - 1) / 2) & 1) s = -s;   // reverse() on 2nd operand
            t.sgn[j][k] = (signed char)s;
            t.idx[j][k] = (unsigned char)inv[(int)(a ^ b)];
        }
    }
    return t;
}

// Packing of the 16 blades into 8 float2 slots, paired by the e1 bit.
struct Packing {
    unsigned char pl[8], ph[8];
    unsigned char slot[16], half[16];
    signed char   act[16][8];
    unsigned char src[16][8];
    unsigned char swp[16][8];
    signed char   s0[16][8], s1[16][8];
};

constexpr Packing make_packing() {
    Packing p{};
    int inv[16] = {};
    for (int i = 0; i < 16; ++i) inv[(int)MASKV[i]] = i;

    int t = 0;
    for (int e0bit = 0; e0bit <= 1; ++e0bit) {
        for (unsigned m = 0; m < 16; ++m) {
            if ((m & 2u) == 0u && (int)(m & 1u) == e0bit) {
                int lo = inv[(int)m], hi = inv[(int)(m | 2u)];
                p.pl[t] = (unsigned char)lo;
                p.ph[t] = (unsigned char)hi;
                p.slot[lo] = (unsigned char)t; p.half[lo] = 0;
                p.slot[hi] = (unsigned char)t; p.half[hi] = 1;
                ++t;
            }
        }
    }

    GPTab tab = make_tab();
    for (int k = 0; k < 16; ++k) {
        for (int s = 0; s < 8; ++s) {
            int i0 = p.pl[s], i1 = p.ph[s];
            int j0 = inv[(int)(MASKV[i0] ^ MASKV[k])];
            int j1 = inv[(int)(MASKV[i1] ^ MASKV[k])];
            int g0 = tab.sgn[j0][k], g1 = tab.sgn[j1][k];
            p.act[k][s] = (signed char)(g0 != 0);
            p.src[k][s] = p.slot[j0];
            p.swp[k][s] = p.half[j0];
            p.s0[k][s] = (signed char)g0;
            p.s1[k][s] = (signed char)g1;
        }
    }
    return p;
}

constexpr Packing PK = make_packing();

} // namespace

// Requires nrows % 256 == 0 (harness: nrows = 2048).
__global__ __launch_bounds__(256) void gp_fused_kernel(
    const float* __restrict__ T, float* __restrict__ out, int nrows) {
    const int lane = threadIdx.x & 63;
    const int wave = threadIdx.x >> 6;
    const int t    = threadIdx.x;
    const int m0   = blockIdx.x * 256;
    const int n    = blockIdx.y;              // wave-uniform

    // 256 pairs x 20-float padded stride (80 B, 16B-aligned). 20 KB.
    // Used twice: (1) b-operand tile, (2) per-wave output store-transpose.
    __shared__ float lds[256 * 20];

    // ---- stage b-tile: 16 KB contiguous from T, fully coalesced ----
    {
        const f4* __restrict__ src =
            reinterpret_cast<const f4*>(T) + (size_t)m0 * 4;
#pragma unroll
        for (int k2 = 0; k2 < 4; ++k2) {
            const int g = k2 * 256 + t;       // float4 id within the tile
            f4 v = src[g];
            const int p = g >> 2, c = g & 3;
            *reinterpret_cast<f4*>(&lds[p * 20 + c * 4]) = v;
        }
    }
    __syncthreads();                          // the only barrier

    // ---- operands ----
    float a[16], b[16];
#pragma unroll
    for (int q = 0; q < 4; ++q) {             // uniform -> scalar/broadcast
        f4 va = reinterpret_cast<const f4*>(T)[(size_t)n * 4 + q];
        a[q * 4 + 0] = va.x; a[q * 4 + 1] = va.y;
        a[q * 4 + 2] = va.z; a[q * 4 + 3] = va.w;
    }
#pragma unroll
    for (int q = 0; q < 4; ++q) {
        f4 vb = *reinterpret_cast<const f4*>(&lds[t * 20 + q * 4]);
        b[q * 4 + 0] = vb.x; b[q * 4 + 1] = vb.y;
        b[q * 4 + 2] = vb.z; b[q * 4 + 3] = vb.w;
    }

    // ---- packed geometric product (96 v_pk_fma_f32) ----
    f2 A[8];
#pragma unroll
    for (int s = 0; s < 8; ++s) {
        f2 v; v.x = a[PK.pl[s]]; v.y = a[PK.ph[s]];
        A[s] = v;
    }

    f2 O[8];
#pragma unroll
    for (int s = 0; s < 8; ++s) O[s] = (f2)(0.0f);

#pragma unroll
    for (int k = 0; k < 16; ++k) {
        const float bk = b[k];
        f2 bb; bb.x = bk; bb.y = bk;
#pragma unroll
        for (int s = 0; s < 8; ++s) {
            if (PK.act[k][s]) {               // compile-time after unroll
                const f2 srcv = A[PK.src[k][s]];
                float x = PK.swp[k][s] ? srcv.y : srcv.x;
                float y = PK.swp[k][s] ? srcv.x : srcv.y;
                if (PK.s0[k][s] < 0) x = -x;
                if (PK.s1[k][s] < 0) y = -y;
                f2 av; av.x = x; av.y = y;
                O[s] = __builtin_elementwise_fma(av, bb, O[s]);
            }
        }
    }

    float o[16];
#pragma unroll
    for (int i = 0; i < 16; ++i)
        o[i] = PK.half[i] ? O[PK.slot[i]].y : O[PK.slot[i]].x;

    // ---- output store-transpose, reusing the SAME LDS region ----
    // Thread t overwrites exactly the region it (alone) read b from; the
    // readback stays within this wave's 64-pair region, so same-wave DS
    // program ordering makes this barrier-free.
    float* w = &lds[t * 20];
#pragma unroll
    for (int q = 0; q < 4; ++q) {
        f4 v; v.x = o[q * 4 + 0]; v.y = o[q * 4 + 1];
        v.z = o[q * 4 + 2]; v.w = o[q * 4 + 3];
        *reinterpret_cast<f4*>(w + q * 4) = v;
    }

    const int waveM0 = m0 + wave * 64;
    f4* __restrict__ ov =
        reinterpret_cast<f4*>(out) + ((size_t)n * nrows + waveM0) * 4;
    const float* wbase = &lds[wave * 64 * 20];
#pragma unroll
    for (int q = 0; q < 4; ++q) {
        const int g = q * 64 + lane;          // float4 index within wave tile
        const int p = g >> 2;
        const int c = g & 3;
        f4 v = *reinterpret_cast<const f4*>(&wbase[p * 20 + c * 4]);
        ov[g] = v;                            // plain store -> L2 write-combine
    }
}

extern "C" void kernel_launch(void* const* d_in, const int* in_sizes, int n_in,
                              void* d_out, int out_size, void* d_ws, size_t ws_size,
                              hipStream_t stream) {
    const float* T = (const float*)d_in[0];
    float* out = (float*)d_out;
    const int nrows = in_sizes[0] / 16;       // 2048 (multiple of 256)
    dim3 grid((unsigned)(nrows / 256), (unsigned)nrows, 1);
    gp_fused_kernel<<<grid, 256, 0, stream>>>(T, out, nrows);
}

// Round 11
// 46.612 us; speedup vs baseline: 1.4046x; 1.1518x over previous
//
#include <hip/hip_runtime.h>

// PGA G(3,0,1) geometric product, pairwise: out[n,m,:] = T[n] * reverse(T[m]).
// R5 (resubmit x3 after infra failures): fused, zero barriers. b read directly
// from global (per-lane strided f4; T is 128 KB = L2-resident, amplification
// is L1-side only). a via wave-uniform scalar loads (SGPRs). Scalar FMAs (pk
// proven neutral in R3) to keep VGPR<=64 for 8 waves/SIMD. LDS used once:
// same-wave store transpose (in-order DS within a wave -> no __syncthreads).
// Plain dwordx4 stores (NT proven -12us in R3b/R4).

namespace {

typedef float f4 __attribute__((ext_vector_type(4)));

constexpr int popcount4(unsigned x) {
    int c = 0;
    for (int i = 0; i < 5; ++i) c += (x >> i) & 1;
    return c;
}

struct GPTab {
    signed char sgn[16][16];   // sign of e_j * e_k (rev on k folded in); 0 if vanishes
    unsigned char idx[16][16]; // output blade index of e_j * e_k
};

// Blade bitmasks in the reference's basis order:
// (), e0..e3, e01,e02,e03,e12,e13,e23, e012,e013,e023,e123, e0123
constexpr unsigned MASKV[16] = {0u, 1u, 2u, 4u, 8u,
                                3u, 5u, 9u, 6u, 10u, 12u,
                                7u, 11u, 13u, 14u, 15u};

constexpr GPTab make_tab() {
    GPTab t{};
    int inv[16] = {};
    for (int i = 0; i < 16; ++i) inv[(int)MASKV[i]] = i;

    for (int j = 0; j < 16; ++j) {
        for (int k = 0; k < 16; ++k) {
            unsigned a = MASKV[j], b = MASKV[k];
            if (a & b & 1u) {            // shared e0 -> e0^2 = 0
                t.sgn[j][k] = 0;
                t.idx[j][k] = 0;
                continue;
            }
            int swaps = 0;
            for (int g = 0; g < 4; ++g)
                if ((b >> g) & 1u)
                    swaps += popcount4(a >> (g + 1));
            int s = (swaps & 1) ? -1 : 1;
            int r = popcount4(b);
            if ((r * (r - 1) / 2) & 1) s = -s;   // reverse() on 2nd operand
            t.sgn[j][k] = (signed char)s;
            t.idx[j][k] = (unsigned char)inv[(int)(a ^ b)];
        }
    }
    return t;
}

constexpr GPTab TAB = make_tab();

} // namespace

// Requires nrows % 256 == 0 (harness: nrows = 2048).
__global__ __launch_bounds__(256) void gp_fused_kernel(
    const float* __restrict__ T, float* __restrict__ out, int nrows) {
    const int lane = threadIdx.x & 63;
    const int wave = threadIdx.x >> 6;
    const int t    = threadIdx.x;
    const int m0   = blockIdx.x * 256;
    const int n    = blockIdx.y;              // wave-uniform

    // Per-wave 64-pair store-transpose region, padded stride 20 floats. 20 KB.
    __shared__ float lds[256 * 20];

    // ---- b: this thread's own pair, direct strided f4 loads (L2-resident) ----
    float b[16];
    {
        const f4* __restrict__ Tb = reinterpret_cast<const f4*>(T) + (size_t)(m0 + t) * 4;
#pragma unroll
        for (int q = 0; q < 4; ++q) {
            f4 v = Tb[q];
            b[q * 4 + 0] = v.x; b[q * 4 + 1] = v.y;
            b[q * 4 + 2] = v.z; b[q * 4 + 3] = v.w;
        }
    }

    // ---- a: wave-uniform -> scalar loads (SGPRs) ----
    float a[16];
    {
        const float* __restrict__ An = T + (size_t)n * 16;
#pragma unroll
        for (int j = 0; j < 16; ++j) a[j] = An[j];
    }

    // ---- geometric product: 192 scalar FMAs, table-driven ----
    float o[16];
#pragma unroll
    for (int i = 0; i < 16; ++i) o[i] = 0.0f;

#pragma unroll
    for (int j = 0; j < 16; ++j) {
#pragma unroll
        for (int k = 0; k < 16; ++k) {
            const int s = TAB.sgn[j][k];      // compile-time after unroll
            const int i = TAB.idx[j][k];
            if (s == 1) {
                o[i] = fmaf(a[j], b[k], o[i]);
            } else if (s == -1) {
                o[i] = fmaf(-a[j], b[k], o[i]);
            }
        }
    }

    // ---- same-wave LDS store-transpose (no barrier: in-order DS per wave) ----
    float* w = &lds[t * 20];
#pragma unroll
    for (int q = 0; q < 4; ++q) {
        f4 v; v.x = o[q * 4 + 0]; v.y = o[q * 4 + 1];
        v.z = o[q * 4 + 2]; v.w = o[q * 4 + 3];
        *reinterpret_cast<f4*>(w + q * 4) = v;
    }

    const int waveM0 = m0 + wave * 64;
    f4* __restrict__ ov =
        reinterpret_cast<f4*>(out) + ((size_t)n * nrows + waveM0) * 4;
    const float* wbase = &lds[wave * 64 * 20];
#pragma unroll
    for (int q = 0; q < 4; ++q) {
        const int g = q * 64 + lane;          // float4 index within wave tile
        const int p = g >> 2;
        const int c = g & 3;
        f4 v = *reinterpret_cast<const f4*>(&wbase[p * 20 + c * 4]);
        ov[g] = v;                            // coalesced 1 KB/instr
    }
}

extern "C" void kernel_launch(void* const* d_in, const int* in_sizes, int n_in,
                              void* d_out, int out_size, void* d_ws, size_t ws_size,
                              hipStream_t stream) {
    const float* T = (const float*)d_in[0];
    float* out = (float*)d_out;
    const int nrows = in_sizes[0] / 16;       // 2048 (multiple of 256)
    dim3 grid((unsigned)(nrows / 256), (unsigned)nrows, 1);
    gp_fused_kernel<<<grid, 256, 0, stream>>>(T, out, nrows);
}

// Round 12
// 45.247 us; speedup vs baseline: 1.4470x; 1.0302x over previous
//
#include <hip/hip_runtime.h>

// PGA G(3,0,1) geometric product, pairwise: out[n,m,:] = T[n] * reverse(T[m]).
// R6: R5 + n-blocking (NB=2). Each thread computes pairs (n0,m) and (n0+1,m):
// b loaded once per thread (halves divergent b-load traffic), a for both n via
// scalar loads, LDS store-transpose region reused sequentially (same-wave DS
// ordering -> still zero barriers), grid halved. Plain dwordx4 stores.

namespace {

typedef float f4 __attribute__((ext_vector_type(4)));

constexpr int popcount4(unsigned x) {
    int c = 0;
    for (int i = 0; i < 5; ++i) c += (x >> i) & 1;
    return c;
}

struct GPTab {
    signed char sgn[16][16];   // sign of e_j * e_k (rev on k folded in); 0 if vanishes
    unsigned char idx[16][16]; // output blade index of e_j * e_k
};

// Blade bitmasks in the reference's basis order:
// (), e0..e3, e01,e02,e03,e12,e13,e23, e012,e013,e023,e123, e0123
constexpr unsigned MASKV[16] = {0u, 1u, 2u, 4u, 8u,
                                3u, 5u, 9u, 6u, 10u, 12u,
                                7u, 11u, 13u, 14u, 15u};

constexpr GPTab make_tab() {
    GPTab t{};
    int inv[16] = {};
    for (int i = 0; i < 16; ++i) inv[(int)MASKV[i]] = i;

    for (int j = 0; j < 16; ++j) {
        for (int k = 0; k < 16; ++k) {
            unsigned a = MASKV[j], b = MASKV[k];
            if (a & b & 1u) {            // shared e0 -> e0^2 = 0
                t.sgn[j][k] = 0;
                t.idx[j][k] = 0;
                continue;
            }
            int swaps = 0;
            for (int g = 0; g < 4; ++g)
                if ((b >> g) & 1u)
                    swaps += popcount4(a >> (g + 1));
            int s = (swaps & 1) ? -1 : 1;
            int r = popcount4(b);
            if ((r * (r - 1) / 2) & 1) s = -s;   // reverse() on 2nd operand
            t.sgn[j][k] = (signed char)s;
            t.idx[j][k] = (unsigned char)inv[(int)(a ^ b)];
        }
    }
    return t;
}

constexpr GPTab TAB = make_tab();

} // namespace

// Requires nrows % 256 == 0 and nrows even (harness: nrows = 2048).
__global__ __launch_bounds__(256) void gp_fused_kernel(
    const float* __restrict__ T, float* __restrict__ out, int nrows) {
    const int lane = threadIdx.x & 63;
    const int wave = threadIdx.x >> 6;
    const int t    = threadIdx.x;
    const int m0   = blockIdx.x * 256;
    const int n0   = blockIdx.y * 2;          // wave-uniform; two n per thread

    // Per-wave 64-pair store-transpose region, padded stride 20 floats. 20 KB.
    __shared__ float lds[256 * 20];

    // ---- b: this thread's own pair, direct strided f4 loads (L2-resident) ----
    float b[16];
    {
        const f4* __restrict__ Tb = reinterpret_cast<const f4*>(T) + (size_t)(m0 + t) * 4;
#pragma unroll
        for (int q = 0; q < 4; ++q) {
            f4 v = Tb[q];
            b[q * 4 + 0] = v.x; b[q * 4 + 1] = v.y;
            b[q * 4 + 2] = v.z; b[q * 4 + 3] = v.w;
        }
    }

    const int waveM0 = m0 + wave * 64;
    const float* wbase = &lds[wave * 64 * 20];
    float* w = &lds[t * 20];

#pragma unroll
    for (int nn = 0; nn < 2; ++nn) {
        const int n = n0 + nn;

        // ---- a: wave-uniform -> scalar loads (SGPRs) ----
        float a[16];
        {
            const float* __restrict__ An = T + (size_t)n * 16;
#pragma unroll
            for (int j = 0; j < 16; ++j) a[j] = An[j];
        }

        // ---- geometric product: 192 scalar FMAs, table-driven ----
        float o[16];
#pragma unroll
        for (int i = 0; i < 16; ++i) o[i] = 0.0f;

#pragma unroll
        for (int j = 0; j < 16; ++j) {
#pragma unroll
            for (int k = 0; k < 16; ++k) {
                const int s = TAB.sgn[j][k];  // compile-time after unroll
                const int i = TAB.idx[j][k];
                if (s == 1) {
                    o[i] = fmaf(a[j], b[k], o[i]);
                } else if (s == -1) {
                    o[i] = fmaf(-a[j], b[k], o[i]);
                }
            }
        }

        // ---- same-wave LDS store-transpose (no barrier; region reused across
        //      nn — per-wave in-order DS makes write-after-read safe) ----
#pragma unroll
        for (int q = 0; q < 4; ++q) {
            f4 v; v.x = o[q * 4 + 0]; v.y = o[q * 4 + 1];
            v.z = o[q * 4 + 2]; v.w = o[q * 4 + 3];
            *reinterpret_cast<f4*>(w + q * 4) = v;
        }

        f4* __restrict__ ov =
            reinterpret_cast<f4*>(out) + ((size_t)n * nrows + waveM0) * 4;
#pragma unroll
        for (int q = 0; q < 4; ++q) {
            const int g = q * 64 + lane;      // float4 index within wave tile
            const int p = g >> 2;
            const int c = g & 3;
            f4 v = *reinterpret_cast<const f4*>(&wbase[p * 20 + c * 4]);
            ov[g] = v;                        // coalesced 1 KB/instr
        }
    }
}

extern "C" void kernel_launch(void* const* d_in, const int* in_sizes, int n_in,
                              void* d_out, int out_size, void* d_ws, size_t ws_size,
                              hipStream_t stream) {
    const float* T = (const float*)d_in[0];
    float* out = (float*)d_out;
    const int nrows = in_sizes[0] / 16;       // 2048 (multiple of 256, even)
    dim3 grid((unsigned)(nrows / 256), (unsigned)(nrows / 2), 1);
    gp_fused_kernel<<<grid, 256, 0, stream>>>(T, out, nrows);
}